// Round 25
// baseline (143.741 us; speedup 1.0000x reference)
//
#include <hip/hip_runtime.h>
#include <hip/hip_bf16.h>

typedef __bf16 bf16;
typedef __attribute__((ext_vector_type(8))) __bf16 bf16x8;
typedef __attribute__((ext_vector_type(4))) float f32x4;

#define S_LEN 2048
#define DM 2048
#define NH 32
#define HD 64
#define QKV_LD 6144
// SCALE * log2(e): QK^T scores land directly in log2 domain
#define SCALE2 0.18033688011112042f
#define DEFER_THR 8.0f

// 2^x via v_exp_f32 (gfx9 v_exp IS base-2 exp).
__device__ __forceinline__ float fast_exp2(float x) {
  return __builtin_amdgcn_exp2f(x);
}

// Async global->LDS, 16B per lane. LDS dest must be wave-uniform base; data
// lands at base + lane*16.
__device__ __forceinline__ void gload_lds16(const bf16* g, const bf16* l) {
  __builtin_amdgcn_global_load_lds(
      (const __attribute__((address_space(1))) void*)(uintptr_t)g,
      (__attribute__((address_space(3))) void*)(uint32_t)(uintptr_t)l,
      16, 0, 0);
}

// DPP cross-lane move (VALU pipe — no LDS latency).
template <int CTRL>
__device__ __forceinline__ float fdpp(float x) {
  return __builtin_bit_cast(float,
      __builtin_amdgcn_update_dpp(0, __builtin_bit_cast(int, x), CTRL, 0xF, 0xF, true));
}
// Exact 16-lane butterfly all-reduce: masks {1,2,7,15} are GF(2)-independent.
__device__ __forceinline__ float red16_max(float x) {
  x = fmaxf(x, fdpp<0xB1>(x));    // quad_perm [1,0,3,2]  : xor 1
  x = fmaxf(x, fdpp<0x4E>(x));    // quad_perm [2,3,0,1]  : xor 2
  x = fmaxf(x, fdpp<0x141>(x));   // row_half_mirror      : xor 7
  x = fmaxf(x, fdpp<0x140>(x));   // row_mirror           : xor 15
  return x;
}

// ---------------------------------------------------------------------------
// f32 -> bf16 conversion (hidden only; weights now converted in-GEMM)
// ---------------------------------------------------------------------------
__global__ __launch_bounds__(256) void cvt_f32_bf16(
    const float* __restrict__ src, bf16* __restrict__ dst, const int n8)
{
  const int stride = gridDim.x * blockDim.x;
  for (int i = blockIdx.x * blockDim.x + threadIdx.x; i < n8; i += stride) {
    const f32x4 a = *(const f32x4*)(src + (size_t)i * 8);
    const f32x4 b = *(const f32x4*)(src + (size_t)i * 8 + 4);
    bf16x8 r;
    r[0] = (bf16)a[0]; r[1] = (bf16)a[1]; r[2] = (bf16)a[2]; r[3] = (bf16)a[3];
    r[4] = (bf16)b[0]; r[5] = (bf16)b[1]; r[6] = (bf16)b[2]; r[7] = (bf16)b[3];
    *(bf16x8*)(dst + (size_t)i * 8) = r;
  }
}

// ---------------------------------------------------------------------------
// GEMM compute / epilogue helpers (verified fragment + swizzle formulas).
// ---------------------------------------------------------------------------
template <int BM, int BN, int WRN, int WCN, typename TO>
__device__ __forceinline__ void gemm_compute_tile(
    const bf16* __restrict__ Ab, f32x4 (*acc)[BN / WCN / 16],
    const int wr, const int wc, const int lq, const int seg)
{
  constexpr int WM = BM / WRN, WN = BN / WCN;
  constexpr int MI = WM / 16, NI = WN / 16;
  const bf16* Bb = Ab + BM * 64;
#pragma unroll
  for (int kk = 0; kk < 2; ++kk) {
    bf16x8 af[MI], bfr[NI];
#pragma unroll
    for (int i = 0; i < MI; ++i) {
      const int row = wr * WM + (i << 4) + lq;
      af[i] = *(const bf16x8*)(Ab + row * 64 +
               ((((kk << 2) + seg) ^ (row & 7)) << 3));
    }
#pragma unroll
    for (int j = 0; j < NI; ++j) {
      const int row = wc * WN + (j << 4) + lq;
      bfr[j] = *(const bf16x8*)(Bb + row * 64 +
               ((((kk << 2) + seg) ^ (row & 7)) << 3));
    }
    __builtin_amdgcn_s_setprio(1);
#pragma unroll
    for (int i = 0; i < MI; ++i)
#pragma unroll
      for (int j = 0; j < NI; ++j)
        acc[i][j] = __builtin_amdgcn_mfma_f32_16x16x32_bf16(af[i], bfr[j], acc[i][j], 0, 0, 0);
    __builtin_amdgcn_s_setprio(0);
  }
}

template <int BM, int BN, int WRN, int WCN, typename TO>
__device__ __forceinline__ void gemm_epilogue(
    f32x4 (*acc)[BN / WCN / 16], const float* __restrict__ bias,
    TO* __restrict__ C, const int N, const int row0, const int col0,
    const int wr, const int wc, const int lq, const int seg)
{
  constexpr int WM = BM / WRN, WN = BN / WCN;
  constexpr int MI = WM / 16, NI = WN / 16;
#pragma unroll
  for (int j = 0; j < NI; ++j) {
    const int col = col0 + wc * WN + (j << 4) + lq;
    const float bv = bias[col];
#pragma unroll
    for (int i = 0; i < MI; ++i) {
      const int rbase = row0 + wr * WM + (i << 4) + (seg << 2);
#pragma unroll
      for (int r = 0; r < 4; ++r)
        C[(size_t)(rbase + r) * N + col] = (TO)(acc[i][j][r] + bv);
    }
  }
}

// ---------------------------------------------------------------------------
// Mixed-staging pipelined GEMM: C[M][N] = A(bf16) @ W(f32)^T + bias.
// A staged via global_load_lds (linear dest + pre-swizzled source).
// W staged via T14 write-late reg-conversion: f32 loads issued at iter start
// (full compute phase of flight), convert+ds_write AFTER compute(t), then
// __syncthreads (vmcnt+lgkm drain needed for ds_write visibility).
// Removes the separate weight-conversion pass (~99 MB HBM traffic).
// LDS content identical to the verified bf16 path -> same swizzled reads.
// ---------------------------------------------------------------------------
template <int BM, int BN, int WRN, int WCN, int NT, int MINW, typename TO>
__global__ __launch_bounds__(NT, MINW) void gemm_mix(
    const bf16* __restrict__ A, const float* __restrict__ Wf,
    const float* __restrict__ bias, TO* __restrict__ C,
    const int M, const int N, const int K)
{
  constexpr int CA = (BM * 64 * 2) / (NT * 16);   // A 16B chunks per thread
  constexpr int CB = (BN * 64 * 2) / (NT * 16);   // W 16B chunks per thread
  constexpr int BUFE = (BM + BN) * 64;
  __shared__ __align__(16) bf16 lds[2 * BUFE];
  const int tid = threadIdx.x, lane = tid & 63, wid = tid >> 6;
  const int wr = wid / WCN, wc = wid % WCN;
  const int row0 = blockIdx.y * BM, col0 = blockIdx.x * BN;
  const int lq = lane & 15, seg = lane >> 4;

  const f32x4 fz = {0.f, 0.f, 0.f, 0.f};
  f32x4 acc[BM / WRN / 16][BN / WCN / 16];
#pragma unroll
  for (int i = 0; i < BM / WRN / 16; ++i)
#pragma unroll
    for (int j = 0; j < BN / WCN / 16; ++j) acc[i][j] = fz;

  auto stageA = [&](const int kt, bf16* Ab) {
    const int k0 = kt << 6;
#pragma unroll
    for (int c = 0; c < CA; ++c) {
      const int off16 = c * NT + tid;
      const int row = off16 >> 3;
      const int ch  = (off16 & 7) ^ (row & 7);     // pre-swizzled source
      gload_lds16(A + (size_t)(row0 + row) * K + k0 + (ch << 3),
                  Ab + (size_t)(c * NT + (wid << 6)) * 8);
    }
  };
  auto loadW = [&](const int kt, f32x4 (&w)[CB][2]) {
    const int k0 = kt << 6;
#pragma unroll
    for (int c = 0; c < CB; ++c) {
      const int off16 = c * NT + tid;
      const int row = off16 >> 3;
      const int ch  = (off16 & 7) ^ (row & 7);     // pre-swizzled source
      const float* p = Wf + (size_t)(col0 + row) * K + k0 + (ch << 3);
      w[c][0] = *(const f32x4*)p;
      w[c][1] = *(const f32x4*)(p + 4);
    }
  };
  auto writeW = [&](bf16* Bb, const f32x4 (&w)[CB][2]) {
#pragma unroll
    for (int c = 0; c < CB; ++c) {
      bf16x8 r;
#pragma unroll
      for (int j = 0; j < 4; ++j) {
        r[j]     = (bf16)w[c][0][j];
        r[4 + j] = (bf16)w[c][1][j];
      }
      // linear dest == what gload_lds would fill: (c*NT + tid)*8 elems
      *(bf16x8*)(Bb + (size_t)(c * NT + tid) * 8) = r;
    }
  };

  const int nt = K >> 6;
  {
    f32x4 w0[CB][2];
    stageA(0, lds);
    loadW(0, w0);
    writeW(lds + BM * 64, w0);
  }
  __syncthreads();   // drains vmcnt (A gload) + lgkm (W writes): buf0 ready

  for (int t = 0; t < nt; ++t) {
    f32x4 wn[CB][2];
    const bool more = (t + 1 < nt);
    if (more) {
      stageA(t + 1, lds + ((t + 1) & 1) * BUFE);   // gload flies over compute
      loadW(t + 1, wn);                            // f32 loads fly over compute
    }
    gemm_compute_tile<BM, BN, WRN, WCN, TO>(lds + (t & 1) * BUFE, acc,
                                            wr, wc, lq, seg);
    if (more)
      writeW(lds + ((t + 1) & 1) * BUFE + BM * 64, wn);  // write-late (T14)
    __syncthreads();   // all of tile t+1 (A gload + W writes) visible
  }
  gemm_epilogue<BM, BN, WRN, WCN, TO>(acc, bias, C, N, row0, col0,
                                      wr, wc, lq, seg);
}

// ---------------------------------------------------------------------------
// Per-q-tile flash state (one 16-row slice per wave).
// m: ONE max per thread's 4-row group. ls: row-sums via ones-MFMA.
// ---------------------------------------------------------------------------
struct QTile {
  bf16x8 qf[2];    // pre-scaled by SCALE*log2e
  f32x4  o[4];
  f32x4  ls;       // l per row (from P @ ones)
  float  m;        // shared group max
};

__device__ __forceinline__ void qtile_init(QTile& st, const bf16* Qg,
                                           const int lq, const int seg) {
  const bf16x8 r0 = *(const bf16x8*)(Qg + (size_t)lq * QKV_LD + seg * 8);
  const bf16x8 r1 = *(const bf16x8*)(Qg + (size_t)lq * QKV_LD + 32 + seg * 8);
#pragma unroll
  for (int j = 0; j < 8; ++j) {
    st.qf[0][j] = (bf16)((float)r0[j] * SCALE2);
    st.qf[1][j] = (bf16)((float)r1[j] * SCALE2);
  }
  const f32x4 fz = {0.f, 0.f, 0.f, 0.f};
#pragma unroll
  for (int r = 0; r < 4; ++r) st.o[r] = fz;
  st.ls = fz;
  st.m = -1e30f;
}

// QK^T -> mask -> online softmax (log2, shared group max, defer-max) -> PV.
__device__ __forceinline__ void qtile_step(
    QTile& st, const int qb, const int nt,
    const int ws, const int lq, const int seg,
    const bf16 (&Ks)[64][64], const bf16 (&Vt)[64][64], bf16 (&Psw)[16][64])
{
  const f32x4 fz = {0.f, 0.f, 0.f, 0.f};
  f32x4 s[4];
  __builtin_amdgcn_s_setprio(1);
#pragma unroll
  for (int ct = 0; ct < 4; ++ct) {
    s[ct] = fz;
#pragma unroll
    for (int ks = 0; ks < 2; ++ks) {
      const int blk = ((ks << 2) + seg) ^ (lq & 7);
      const bf16x8 kf = *(const bf16x8*)(&Ks[(ct << 4) + lq][blk << 3]);
      s[ct] = __builtin_amdgcn_mfma_f32_16x16x32_bf16(st.qf[ks], kf, s[ct], 0, 0, 0);
    }
  }
  __builtin_amdgcn_s_setprio(0);

  // causal mask (diagonal tile only); scores already scaled via Q
  if (nt == qb) {
#pragma unroll
    for (int ct = 0; ct < 4; ++ct) {
      const int key = (nt << 6) + (ct << 4) + lq;
#pragma unroll
      for (int r = 0; r < 4; ++r) {
        const int qrow = (qb << 6) + (ws << 4) + (seg << 2) + r;
        if (key > qrow) s[ct][r] = -1e30f;
      }
    }
  }

  // shared group max (4 rows x 64 keys of this thread's lane-group)
  float tm = s[0][0];
#pragma unroll
  for (int ct = 0; ct < 4; ++ct)
#pragma unroll
    for (int r = 0; r < 4; ++r) tm = fmaxf(tm, s[ct][r]);
  tm = red16_max(tm);
  if (tm > st.m + DEFER_THR) {         // rescale path (rare)
    const float sc = fast_exp2(st.m - tm);
    st.m = tm;
    st.ls *= sc;
#pragma unroll
    for (int dt = 0; dt < 4; ++dt) st.o[dt] *= sc;
  }

  // P = exp2(s - m) -> per-wave LDS (A-frag layout), swizzled cols
#pragma unroll
  for (int ct = 0; ct < 4; ++ct)
#pragma unroll
    for (int r = 0; r < 4; ++r) {
      const int q = (seg << 2) + r;
      const int colp = ((ct << 4) + lq) ^ ((q & 7) << 3);
      Psw[q][colp] = (bf16)fast_exp2(s[ct][r] - st.m);
    }

  // PV: O += P @ V ; row-sums via ones-MFMA (replaces VALU butterfly sum)
  bf16x8 ones;
#pragma unroll
  for (int j = 0; j < 8; ++j) ones[j] = (bf16)1.0f;
  __builtin_amdgcn_s_setprio(1);
#pragma unroll
  for (int ks = 0; ks < 2; ++ks) {
    const int blkp = ((ks << 2) + seg) ^ (lq & 7);
    const bf16x8 af = *(const bf16x8*)(&Psw[lq][blkp << 3]);
    st.ls = __builtin_amdgcn_mfma_f32_16x16x32_bf16(af, ones, st.ls, 0, 0, 0);
#pragma unroll
    for (int dt = 0; dt < 4; ++dt) {
      const int xv = (lq & 7) ^ (((dt << 1) + (lq >> 3)) & 7);
      const int blkv = ((ks << 2) + seg) ^ xv;
      const bf16x8 bv = *(const bf16x8*)(&Vt[(dt << 4) + lq][blkv << 3]);
      st.o[dt] = __builtin_amdgcn_mfma_f32_16x16x32_bf16(af, bv, st.o[dt], 0, 0, 0);
    }
  }
  __builtin_amdgcn_s_setprio(0);
}

__device__ __forceinline__ void qtile_store(
    const QTile& st, bf16* __restrict__ out, const int qb, const int h,
    const int ws, const int lq, const int seg)
{
  float rinv[4];
#pragma unroll
  for (int r = 0; r < 4; ++r) rinv[r] = 1.f / st.ls[r];
#pragma unroll
  for (int dt = 0; dt < 4; ++dt)
#pragma unroll
    for (int r = 0; r < 4; ++r) {
      const int qrow = (qb << 6) + (ws << 4) + (seg << 2) + r;
      out[(size_t)qrow * DM + h * HD + (dt << 4) + lq] =
          (bf16)(st.o[dt][r] * rinv[r]);
    }
}

// ---------------------------------------------------------------------------
// Flash-style causal attention, 8-wave blocks, wrap-paired q-tiles,
// XCD head-grouping (each XCD owns 4 heads -> KV stays in its L2),
// double-buffered KV with ONE barrier per tile (T14 write-late split).
// [R17/R21-verified configuration — session best.]
// ---------------------------------------------------------------------------
__global__ __launch_bounds__(512, 4) void attn_flash(
    const bf16* __restrict__ qkv, bf16* __restrict__ out)
{
  __shared__ __align__(16) bf16 Ks[2][64][64];    // [buf][key][d], col-swizzled
  __shared__ __align__(16) bf16 Vt[2][64][64];    // [buf][d][key], key-swizzled
  __shared__ __align__(16) bf16 Ps[8][16][64];    // per-wave P, col-swizzled
  // XCD head-grouping: xcd = bid&7 serves heads 4*xcd..4*xcd+3
  const int bid = blockIdx.x;
  const int xcd = bid & 7, idx = bid >> 3;        // idx 0..63
  const int h   = (xcd << 2) | (idx >> 4);        // 4 heads per XCD
  const int qbA = idx & 15;                       // 0..15 (short range)
  const int qbB = 31 - qbA;                       // 31..16 (long range)
  const int tid = threadIdx.x;
  const int lane = tid & 63, wid = tid >> 6;      // wid 0..7
  const int lq = lane & 15, seg = lane >> 4;
  const int myqb = (wid < 4) ? qbA : qbB;
  const int ws   = wid & 3;                       // 16-row slice within tile

  const bf16* Kg = qkv + DM + h * HD;
  const bf16* Vg = qkv + 2 * DM + h * HD;

  QTile st;
  qtile_init(st, qkv + (size_t)(myqb * 64 + ws * 16) * QKV_LD + h * HD, lq, seg);

  const int srow = tid >> 3, sch = tid & 7;  // staging: row 0..63, chunk 0..7

  // prologue: tile 0 -> buf 0
  {
    const bf16x8 k0 = *(const bf16x8*)(Kg + (size_t)srow * QKV_LD + (sch << 3));
    const bf16x8 v0 = *(const bf16x8*)(Vg + (size_t)srow * QKV_LD + (sch << 3));
    *(bf16x8*)(&Ks[0][srow][(sch ^ (srow & 7)) << 3]) = k0;
#pragma unroll
    for (int j = 0; j < 8; ++j)
      Vt[0][(sch << 3) + j][srow ^ ((j ^ sch) << 3)] = v0[j];
  }
  __syncthreads();

  for (int nt = 0; nt <= qbB; ++nt) {
    // ---- issue next tile's global loads (fly during compute)
    bf16x8 kr, vr;
    if (nt < qbB) {
      const int row = ((nt + 1) << 6) + srow;
      kr = *(const bf16x8*)(Kg + (size_t)row * QKV_LD + (sch << 3));
      vr = *(const bf16x8*)(Vg + (size_t)row * QKV_LD + (sch << 3));
    }

    // ---- compute tile nt from buf[nt&1]
    if (nt <= myqb)
      qtile_step(st, myqb, nt, ws, lq, seg, Ks[nt & 1], Vt[nt & 1], Ps[wid]);

    // ---- write tile nt+1 into buf[(nt+1)&1] (reads of it ended last barrier)
    if (nt < qbB) {
      const int b = (nt + 1) & 1;
      *(bf16x8*)(&Ks[b][srow][(sch ^ (srow & 7)) << 3]) = kr;
#pragma unroll
      for (int j = 0; j < 8; ++j)
        Vt[b][(sch << 3) + j][srow ^ ((j ^ sch) << 3)] = vr[j];
    }
    __syncthreads();   // writes visible; reads of buf[nt&1] complete
  }

  qtile_store(st, out, myqb, h, ws, lq, seg);
}

// ---------------------------------------------------------------------------
extern "C" void kernel_launch(void* const* d_in, const int* in_sizes, int n_in,
                              void* d_out, int out_size, void* d_ws, size_t ws_size,
                              hipStream_t stream) {
  (void)in_sizes; (void)n_in; (void)out_size; (void)ws_size;
  const float* hidden = (const float*)d_in[0];
  const float* w_qkv  = (const float*)d_in[1];
  const float* b_qkv  = (const float*)d_in[2];
  const float* w_out  = (const float*)d_in[3];
  const float* b_out  = (const float*)d_in[4];
  float* out = (float*)d_out;

  bf16* qkvbuf  = (bf16*)d_ws;                            // [2048][6144]
  bf16* attnbuf = qkvbuf  + (size_t)S_LEN * (3 * DM);     // [2048][2048]
  bf16* hidb    = attnbuf + (size_t)S_LEN * DM;           // [2048][2048]

  dim3 blk(256);
  // f32 -> bf16: hidden only (~12 MB traffic); weights convert in-GEMM
  cvt_f32_bf16<<<dim3(2048), blk, 0, stream>>>(hidden, hidb, (S_LEN * DM) / 8);
  // QKV projection: 128x192 tiles, mixed staging (A gload_lds, W f32->bf16)
  gemm_mix<128, 192, 2, 4, 512, 2, bf16><<<dim3(32, 16), dim3(512), 0, stream>>>(
      hidb, w_qkv, b_qkv, qkvbuf, S_LEN, 3 * DM, DM);
  // Flash causal attention: R17/R21-verified (~46us)
  attn_flash<<<dim3(512), dim3(512), 0, stream>>>(qkvbuf, attnbuf);
  // Output projection: 64x128 tiles, mixed staging
  gemm_mix<64, 128, 1, 4, 256, 2, float><<<dim3(16, 32), dim3(256), 0, stream>>>(
      attnbuf, w_out, b_out, out, S_LEN, DM, DM);
}

// Round 26
// 140.699 us; speedup vs baseline: 1.0216x; 1.0216x over previous
//
#include <hip/hip_runtime.h>
#include <hip/hip_bf16.h>

typedef __bf16 bf16;
typedef __attribute__((ext_vector_type(8))) __bf16 bf16x8;
typedef __attribute__((ext_vector_type(4))) float f32x4;

#define S_LEN 2048
#define DM 2048
#define NH 32
#define HD 64
#define QKV_LD 6144
// SCALE * log2(e): QK^T scores land directly in log2 domain
#define SCALE2 0.18033688011112042f
#define DEFER_THR 8.0f

// 2^x via v_exp_f32 (gfx9 v_exp IS base-2 exp).
__device__ __forceinline__ float fast_exp2(float x) {
  return __builtin_amdgcn_exp2f(x);
}

// Async global->LDS, 16B per lane. LDS dest must be wave-uniform base; data
// lands at base + lane*16.
__device__ __forceinline__ void gload_lds16(const bf16* g, const bf16* l) {
  __builtin_amdgcn_global_load_lds(
      (const __attribute__((address_space(1))) void*)(uintptr_t)g,
      (__attribute__((address_space(3))) void*)(uint32_t)(uintptr_t)l,
      16, 0, 0);
}

// Compile-time counted vmcnt (inline asm needs a literal).
template <int N>
__device__ __forceinline__ void waitcnt_vm() {
  if constexpr (N == 0)      asm volatile("s_waitcnt vmcnt(0)" ::: "memory");
  else if constexpr (N == 5) asm volatile("s_waitcnt vmcnt(5)" ::: "memory");
  else if constexpr (N == 6) asm volatile("s_waitcnt vmcnt(6)" ::: "memory");
  else static_assert(N == 0, "add vmcnt case");
}

// DPP cross-lane move (VALU pipe — no LDS latency).
template <int CTRL>
__device__ __forceinline__ float fdpp(float x) {
  return __builtin_bit_cast(float,
      __builtin_amdgcn_update_dpp(0, __builtin_bit_cast(int, x), CTRL, 0xF, 0xF, true));
}
// Exact 16-lane butterfly all-reduce: masks {1,2,7,15} are GF(2)-independent.
__device__ __forceinline__ float red16_max(float x) {
  x = fmaxf(x, fdpp<0xB1>(x));    // quad_perm [1,0,3,2]  : xor 1
  x = fmaxf(x, fdpp<0x4E>(x));    // quad_perm [2,3,0,1]  : xor 2
  x = fmaxf(x, fdpp<0x141>(x));   // row_half_mirror      : xor 7
  x = fmaxf(x, fdpp<0x140>(x));   // row_mirror           : xor 15
  return x;
}

// ---------------------------------------------------------------------------
// Fused f32 -> bf16 conversion over three arrays (one launch, grid-stride)
// ---------------------------------------------------------------------------
__global__ __launch_bounds__(256) void cvt3_f32_bf16(
    const float* __restrict__ s0, bf16* __restrict__ d0, const int n0,
    const float* __restrict__ s1, bf16* __restrict__ d1, const int n1,
    const float* __restrict__ s2, bf16* __restrict__ d2, const int n2)
{
  const int total = n0 + n1 + n2;
  const int stride = gridDim.x * blockDim.x;
  for (int i = blockIdx.x * blockDim.x + threadIdx.x; i < total; i += stride) {
    const float* s; bf16* d; int j = i;
    if (j < n0)            { s = s0; d = d0; }
    else if (j - n0 < n1)  { s = s1; d = d1; j -= n0; }
    else                   { s = s2; d = d2; j -= n0 + n1; }
    const f32x4 a = *(const f32x4*)(s + (size_t)j * 8);
    const f32x4 b = *(const f32x4*)(s + (size_t)j * 8 + 4);
    bf16x8 r;
    r[0] = (bf16)a[0]; r[1] = (bf16)a[1]; r[2] = (bf16)a[2]; r[3] = (bf16)a[3];
    r[4] = (bf16)b[0]; r[5] = (bf16)b[1]; r[6] = (bf16)b[2]; r[7] = (bf16)b[3];
    *(bf16x8*)(d + (size_t)j * 8) = r;
  }
}

// ---------------------------------------------------------------------------
// GEMM staging helper shared by both pipeline variants.
// ---------------------------------------------------------------------------
template <int BM, int BN, int NT>
__device__ __forceinline__ void gemm_stage(
    const bf16* __restrict__ A, const bf16* __restrict__ W,
    bf16* __restrict__ Ab, const int row0, const int col0,
    const int K, const int kt, const int tid, const int wid)
{
  constexpr int CA = (BM * 64 * 2) / (NT * 16);
  constexpr int CB = (BN * 64 * 2) / (NT * 16);
  const int k0 = kt << 6;
  bf16* Bb = Ab + BM * 64;
#pragma unroll
  for (int c = 0; c < CA; ++c) {
    const int off16 = c * NT + tid;
    const int row = off16 >> 3;
    const int ch  = (off16 & 7) ^ (row & 7);      // pre-swizzled source
    gload_lds16(A + (size_t)(row0 + row) * K + k0 + (ch << 3),
                Ab + (size_t)(c * NT + (wid << 6)) * 8);
  }
#pragma unroll
  for (int c = 0; c < CB; ++c) {
    const int off16 = c * NT + tid;
    const int row = off16 >> 3;
    const int ch  = (off16 & 7) ^ (row & 7);
    gload_lds16(W + (size_t)(col0 + row) * K + k0 + (ch << 3),
                Bb + (size_t)(c * NT + (wid << 6)) * 8);
  }
}

template <int BM, int BN, int WRN, int WCN, typename TO>
__device__ __forceinline__ void gemm_compute_tile(
    const bf16* __restrict__ Ab, f32x4 (*acc)[BN / WCN / 16],
    const int wr, const int wc, const int lq, const int seg)
{
  constexpr int WM = BM / WRN, WN = BN / WCN;
  constexpr int MI = WM / 16, NI = WN / 16;
  const bf16* Bb = Ab + BM * 64;
#pragma unroll
  for (int kk = 0; kk < 2; ++kk) {
    bf16x8 af[MI], bfr[NI];
#pragma unroll
    for (int i = 0; i < MI; ++i) {
      const int row = wr * WM + (i << 4) + lq;
      af[i] = *(const bf16x8*)(Ab + row * 64 +
               ((((kk << 2) + seg) ^ (row & 7)) << 3));
    }
#pragma unroll
    for (int j = 0; j < NI; ++j) {
      const int row = wc * WN + (j << 4) + lq;
      bfr[j] = *(const bf16x8*)(Bb + row * 64 +
               ((((kk << 2) + seg) ^ (row & 7)) << 3));
    }
    __builtin_amdgcn_s_setprio(1);
#pragma unroll
    for (int i = 0; i < MI; ++i)
#pragma unroll
      for (int j = 0; j < NI; ++j)
        acc[i][j] = __builtin_amdgcn_mfma_f32_16x16x32_bf16(af[i], bfr[j], acc[i][j], 0, 0, 0);
    __builtin_amdgcn_s_setprio(0);
  }
}

template <int BM, int BN, int WRN, int WCN, typename TO>
__device__ __forceinline__ void gemm_epilogue(
    f32x4 (*acc)[BN / WCN / 16], const float* __restrict__ bias,
    TO* __restrict__ C, const int N, const int row0, const int col0,
    const int wr, const int wc, const int lq, const int seg)
{
  constexpr int WM = BM / WRN, WN = BN / WCN;
  constexpr int MI = WM / 16, NI = WN / 16;
#pragma unroll
  for (int j = 0; j < NI; ++j) {
    const int col = col0 + wc * WN + (j << 4) + lq;
    const float bv = bias[col];
#pragma unroll
    for (int i = 0; i < MI; ++i) {
      const int rbase = row0 + wr * WM + (i << 4) + (seg << 2);
#pragma unroll
      for (int r = 0; r < 4; ++r)
        C[(size_t)(rbase + r) * N + col] = (TO)(acc[i][j][r] + bv);
    }
  }
}

// ---------------------------------------------------------------------------
// Variant 1 (long compute phase, QKV): ONE barrier per K-tile.
// {vmcnt(0); s_barrier; stage(t+1); compute(t)}.  Verified: ~50.7us, 42% Mfma.
// ---------------------------------------------------------------------------
template <int BM, int BN, int WRN, int WCN, int NT, int MINW, typename TO>
__global__ __launch_bounds__(NT, MINW) void gemm_pipe1(
    const bf16* __restrict__ A, const bf16* __restrict__ W,
    const float* __restrict__ bias, TO* __restrict__ C,
    const int M, const int N, const int K)
{
  constexpr int BUFE = (BM + BN) * 64;
  __shared__ __align__(16) bf16 lds[2 * BUFE];
  const int tid = threadIdx.x, lane = tid & 63, wid = tid >> 6;
  const int wr = wid / WCN, wc = wid % WCN;
  const int row0 = blockIdx.y * BM, col0 = blockIdx.x * BN;
  const int lq = lane & 15, seg = lane >> 4;

  const f32x4 fz = {0.f, 0.f, 0.f, 0.f};
  f32x4 acc[BM / WRN / 16][BN / WCN / 16];
#pragma unroll
  for (int i = 0; i < BM / WRN / 16; ++i)
#pragma unroll
    for (int j = 0; j < BN / WCN / 16; ++j) acc[i][j] = fz;

  const int nt = K >> 6;
  gemm_stage<BM, BN, NT>(A, W, lds, row0, col0, K, 0, tid, wid);

  for (int t = 0; t < nt; ++t) {
    asm volatile("s_waitcnt vmcnt(0)" ::: "memory");
    __builtin_amdgcn_s_barrier();
    asm volatile("" ::: "memory");
    if (t + 1 < nt)
      gemm_stage<BM, BN, NT>(A, W, lds + ((t + 1) & 1) * BUFE,
                             row0, col0, K, t + 1, tid, wid);
    gemm_compute_tile<BM, BN, WRN, WCN, TO>(lds + (t & 1) * BUFE, acc,
                                            wr, wc, lq, seg);
  }
  gemm_epilogue<BM, BN, WRN, WCN, TO>(acc, bias, C, N, row0, col0,
                                      wr, wc, lq, seg);
}

// ---------------------------------------------------------------------------
// Variant 2 (short compute phase, out-proj): counted-vmcnt, 2 barriers/tile.
// Loads stay in flight ACROSS the barrier (R10-verified structure).
// ---------------------------------------------------------------------------
template <int BM, int BN, int WRN, int WCN, int NT, int MINW, typename TO>
__global__ __launch_bounds__(NT, MINW) void gemm_pipe2(
    const bf16* __restrict__ A, const bf16* __restrict__ W,
    const float* __restrict__ bias, TO* __restrict__ C,
    const int M, const int N, const int K)
{
  constexpr int CA = (BM * 64 * 2) / (NT * 16);
  constexpr int CB = (BN * 64 * 2) / (NT * 16);
  constexpr int BUFE = (BM + BN) * 64;
  __shared__ __align__(16) bf16 lds[2 * BUFE];
  const int tid = threadIdx.x, lane = tid & 63, wid = tid >> 6;
  const int wr = wid / WCN, wc = wid % WCN;
  const int row0 = blockIdx.y * BM, col0 = blockIdx.x * BN;
  const int lq = lane & 15, seg = lane >> 4;

  const f32x4 fz = {0.f, 0.f, 0.f, 0.f};
  f32x4 acc[BM / WRN / 16][BN / WCN / 16];
#pragma unroll
  for (int i = 0; i < BM / WRN / 16; ++i)
#pragma unroll
    for (int j = 0; j < BN / WCN / 16; ++j) acc[i][j] = fz;

  const int nt = K >> 6;
  gemm_stage<BM, BN, NT>(A, W, lds, row0, col0, K, 0, tid, wid);

  for (int t = 0; t < nt; ++t) {
    asm volatile("" ::: "memory");
    __builtin_amdgcn_s_barrier();                  // frees buf (t+1)&1
    asm volatile("" ::: "memory");
    if (t + 1 < nt) {
      gemm_stage<BM, BN, NT>(A, W, lds + ((t + 1) & 1) * BUFE,
                             row0, col0, K, t + 1, tid, wid);
      waitcnt_vm<CA + CB>();                       // tile-t landed (mine)
    } else {
      waitcnt_vm<0>();
    }
    __builtin_amdgcn_s_barrier();                  // tile t landed (all waves)
    asm volatile("" ::: "memory");
    gemm_compute_tile<BM, BN, WRN, WCN, TO>(lds + (t & 1) * BUFE, acc,
                                            wr, wc, lq, seg);
  }
  gemm_epilogue<BM, BN, WRN, WCN, TO>(acc, bias, C, N, row0, col0,
                                      wr, wc, lq, seg);
}

// ---------------------------------------------------------------------------
// Per-q-tile flash state (one 16-row slice per wave).
// m: ONE max per thread's 4-row group. ls: row-sums via ones-MFMA.
// ---------------------------------------------------------------------------
struct QTile {
  bf16x8 qf[2];    // pre-scaled by SCALE*log2e
  f32x4  o[4];
  f32x4  ls;       // l per row (from P @ ones)
  float  m;        // shared group max
};

__device__ __forceinline__ void qtile_init(QTile& st, const bf16* Qg,
                                           const int lq, const int seg) {
  const bf16x8 r0 = *(const bf16x8*)(Qg + (size_t)lq * QKV_LD + seg * 8);
  const bf16x8 r1 = *(const bf16x8*)(Qg + (size_t)lq * QKV_LD + 32 + seg * 8);
#pragma unroll
  for (int j = 0; j < 8; ++j) {
    st.qf[0][j] = (bf16)((float)r0[j] * SCALE2);
    st.qf[1][j] = (bf16)((float)r1[j] * SCALE2);
  }
  const f32x4 fz = {0.f, 0.f, 0.f, 0.f};
#pragma unroll
  for (int r = 0; r < 4; ++r) st.o[r] = fz;
  st.ls = fz;
  st.m = -1e30f;
}

// QK^T -> mask -> online softmax (log2, shared group max, defer-max) -> PV.
__device__ __forceinline__ void qtile_step(
    QTile& st, const int qb, const int nt,
    const int ws, const int lq, const int seg,
    const bf16 (&Ks)[64][64], const bf16 (&Vt)[64][64], bf16 (&Psw)[16][64])
{
  const f32x4 fz = {0.f, 0.f, 0.f, 0.f};
  f32x4 s[4];
  __builtin_amdgcn_s_setprio(1);
#pragma unroll
  for (int ct = 0; ct < 4; ++ct) {
    s[ct] = fz;
#pragma unroll
    for (int ks = 0; ks < 2; ++ks) {
      const int blk = ((ks << 2) + seg) ^ (lq & 7);
      const bf16x8 kf = *(const bf16x8*)(&Ks[(ct << 4) + lq][blk << 3]);
      s[ct] = __builtin_amdgcn_mfma_f32_16x16x32_bf16(st.qf[ks], kf, s[ct], 0, 0, 0);
    }
  }
  __builtin_amdgcn_s_setprio(0);

  // causal mask (diagonal tile only); scores already scaled via Q
  if (nt == qb) {
#pragma unroll
    for (int ct = 0; ct < 4; ++ct) {
      const int key = (nt << 6) + (ct << 4) + lq;
#pragma unroll
      for (int r = 0; r < 4; ++r) {
        const int qrow = (qb << 6) + (ws << 4) + (seg << 2) + r;
        if (key > qrow) s[ct][r] = -1e30f;
      }
    }
  }

  // shared group max (4 rows x 64 keys of this thread's lane-group)
  float tm = s[0][0];
#pragma unroll
  for (int ct = 0; ct < 4; ++ct)
#pragma unroll
    for (int r = 0; r < 4; ++r) tm = fmaxf(tm, s[ct][r]);
  tm = red16_max(tm);
  if (tm > st.m + DEFER_THR) {         // rescale path (rare)
    const float sc = fast_exp2(st.m - tm);
    st.m = tm;
    st.ls *= sc;
#pragma unroll
    for (int dt = 0; dt < 4; ++dt) st.o[dt] *= sc;
  }

  // P = exp2(s - m) -> per-wave LDS (A-frag layout), swizzled cols
#pragma unroll
  for (int ct = 0; ct < 4; ++ct)
#pragma unroll
    for (int r = 0; r < 4; ++r) {
      const int q = (seg << 2) + r;
      const int colp = ((ct << 4) + lq) ^ ((q & 7) << 3);
      Psw[q][colp] = (bf16)fast_exp2(s[ct][r] - st.m);
    }

  // PV: O += P @ V ; row-sums via ones-MFMA (replaces VALU butterfly sum)
  bf16x8 ones;
#pragma unroll
  for (int j = 0; j < 8; ++j) ones[j] = (bf16)1.0f;
  __builtin_amdgcn_s_setprio(1);
#pragma unroll
  for (int ks = 0; ks < 2; ++ks) {
    const int blkp = ((ks << 2) + seg) ^ (lq & 7);
    const bf16x8 af = *(const bf16x8*)(&Psw[lq][blkp << 3]);
    st.ls = __builtin_amdgcn_mfma_f32_16x16x32_bf16(af, ones, st.ls, 0, 0, 0);
#pragma unroll
    for (int dt = 0; dt < 4; ++dt) {
      const int xv = (lq & 7) ^ (((dt << 1) + (lq >> 3)) & 7);
      const int blkv = ((ks << 2) + seg) ^ xv;
      const bf16x8 bv = *(const bf16x8*)(&Vt[(dt << 4) + lq][blkv << 3]);
      st.o[dt] = __builtin_amdgcn_mfma_f32_16x16x32_bf16(af, bv, st.o[dt], 0, 0, 0);
    }
  }
  __builtin_amdgcn_s_setprio(0);
}

__device__ __forceinline__ void qtile_store(
    const QTile& st, bf16* __restrict__ out, const int qb, const int h,
    const int ws, const int lq, const int seg)
{
  float rinv[4];
#pragma unroll
  for (int r = 0; r < 4; ++r) rinv[r] = 1.f / st.ls[r];
#pragma unroll
  for (int dt = 0; dt < 4; ++dt)
#pragma unroll
    for (int r = 0; r < 4; ++r) {
      const int qrow = (qb << 6) + (ws << 4) + (seg << 2) + r;
      out[(size_t)qrow * DM + h * HD + (dt << 4) + lq] =
          (bf16)(st.o[dt][r] * rinv[r]);
    }
}

// ---------------------------------------------------------------------------
// Flash-style causal attention, 8-wave blocks, wrap-paired q-tiles,
// XCD head-grouping (each XCD owns 4 heads -> KV stays in its L2),
// double-buffered KV with ONE barrier per tile (T14 write-late split).
// [R17/R21-verified configuration — session best.]
// ---------------------------------------------------------------------------
__global__ __launch_bounds__(512, 4) void attn_flash(
    const bf16* __restrict__ qkv, bf16* __restrict__ out)
{
  __shared__ __align__(16) bf16 Ks[2][64][64];    // [buf][key][d], col-swizzled
  __shared__ __align__(16) bf16 Vt[2][64][64];    // [buf][d][key], key-swizzled
  __shared__ __align__(16) bf16 Ps[8][16][64];    // per-wave P, col-swizzled
  // XCD head-grouping: xcd = bid&7 serves heads 4*xcd..4*xcd+3
  const int bid = blockIdx.x;
  const int xcd = bid & 7, idx = bid >> 3;        // idx 0..63
  const int h   = (xcd << 2) | (idx >> 4);        // 4 heads per XCD
  const int qbA = idx & 15;                       // 0..15 (short range)
  const int qbB = 31 - qbA;                       // 31..16 (long range)
  const int tid = threadIdx.x;
  const int lane = tid & 63, wid = tid >> 6;      // wid 0..7
  const int lq = lane & 15, seg = lane >> 4;
  const int myqb = (wid < 4) ? qbA : qbB;
  const int ws   = wid & 3;                       // 16-row slice within tile

  const bf16* Kg = qkv + DM + h * HD;
  const bf16* Vg = qkv + 2 * DM + h * HD;

  QTile st;
  qtile_init(st, qkv + (size_t)(myqb * 64 + ws * 16) * QKV_LD + h * HD, lq, seg);

  const int srow = tid >> 3, sch = tid & 7;  // staging: row 0..63, chunk 0..7

  // prologue: tile 0 -> buf 0
  {
    const bf16x8 k0 = *(const bf16x8*)(Kg + (size_t)srow * QKV_LD + (sch << 3));
    const bf16x8 v0 = *(const bf16x8*)(Vg + (size_t)srow * QKV_LD + (sch << 3));
    *(bf16x8*)(&Ks[0][srow][(sch ^ (srow & 7)) << 3]) = k0;
#pragma unroll
    for (int j = 0; j < 8; ++j)
      Vt[0][(sch << 3) + j][srow ^ ((j ^ sch) << 3)] = v0[j];
  }
  __syncthreads();

  for (int nt = 0; nt <= qbB; ++nt) {
    // ---- issue next tile's global loads (fly during compute)
    bf16x8 kr, vr;
    if (nt < qbB) {
      const int row = ((nt + 1) << 6) + srow;
      kr = *(const bf16x8*)(Kg + (size_t)row * QKV_LD + (sch << 3));
      vr = *(const bf16x8*)(Vg + (size_t)row * QKV_LD + (sch << 3));
    }

    // ---- compute tile nt from buf[nt&1]
    if (nt <= myqb)
      qtile_step(st, myqb, nt, ws, lq, seg, Ks[nt & 1], Vt[nt & 1], Ps[wid]);

    // ---- write tile nt+1 into buf[(nt+1)&1] (reads of it ended last barrier)
    if (nt < qbB) {
      const int b = (nt + 1) & 1;
      *(bf16x8*)(&Ks[b][srow][(sch ^ (srow & 7)) << 3]) = kr;
#pragma unroll
      for (int j = 0; j < 8; ++j)
        Vt[b][(sch << 3) + j][srow ^ ((j ^ sch) << 3)] = vr[j];
    }
    __syncthreads();   // writes visible; reads of buf[nt&1] complete
  }

  qtile_store(st, out, myqb, h, ws, lq, seg);
}

// ---------------------------------------------------------------------------
extern "C" void kernel_launch(void* const* d_in, const int* in_sizes, int n_in,
                              void* d_out, int out_size, void* d_ws, size_t ws_size,
                              hipStream_t stream) {
  (void)in_sizes; (void)n_in; (void)out_size; (void)ws_size;
  const float* hidden = (const float*)d_in[0];
  const float* w_qkv  = (const float*)d_in[1];
  const float* b_qkv  = (const float*)d_in[2];
  const float* w_out  = (const float*)d_in[3];
  const float* b_out  = (const float*)d_in[4];
  float* out = (float*)d_out;

  bf16* qkvbuf  = (bf16*)d_ws;                            // [2048][6144]
  bf16* attnbuf = qkvbuf  + (size_t)S_LEN * (3 * DM);     // [2048][2048]
  bf16* hidb    = attnbuf + (size_t)S_LEN * DM;           // [2048][2048]
  bf16* wqkvb   = hidb    + (size_t)S_LEN * DM;           // [6144][2048]
  bf16* woutb   = wqkvb   + (size_t)(3 * DM) * DM;        // [2048][2048]

  dim3 blk(256);
  // fused f32 -> bf16 conversions (one launch; at HBM roofline ~21us)
  cvt3_f32_bf16<<<dim3(2048), blk, 0, stream>>>(
      hidden, hidb, (S_LEN * DM) / 8,
      w_qkv, wqkvb, (3 * DM * DM) / 8,
      w_out, woutb, (DM * DM) / 8);
  // QKV projection: 128x192 tiles, 1-barrier pipeline (verified ~50.7us)
  gemm_pipe1<128, 192, 2, 4, 512, 2, bf16><<<dim3(32, 16), dim3(512), 0, stream>>>(
      hidb, wqkvb, b_qkv, qkvbuf, S_LEN, 3 * DM, DM);
  // Flash causal attention: R17/R21-verified (~46us)
  attn_flash<<<dim3(512), dim3(512), 0, stream>>>(qkvbuf, attnbuf);
  // Output projection: 64x128 tiles, counted-vmcnt 2-barrier (~13us)
  gemm_pipe2<64, 128, 1, 4, 256, 2, float><<<dim3(16, 32), dim3(256), 0, stream>>>(
      attnbuf, woutb, b_out, out, S_LEN, DM, DM);
}